// Round 6
// 252.336 us; speedup vs baseline: 1.0730x; 1.0730x over previous
//
#include <hip/hip_runtime.h>
#include <math.h>

#define NN 5000
#define NE 160000
#define NF 16
#define KS 640      // k per split (grid.y = 8): 7x640 + 520
#define WTS 648     // LDS k-stride (bf16 units): 648*2B=1296B=324 words,
                    // 324%32=4 -> n..n+8 share a bank (2-way = free, m136)
#define CAP 128     // per-node edge bucket capacity (max in-deg ~65 @ lambda=32)

typedef __attribute__((ext_vector_type(8))) short bf16x8;  // 4 VGPRs
typedef __attribute__((ext_vector_type(4))) float f32x4;   // MFMA acc

// ws layout (bytes):
// [0,       20000)   cur   : int per-node edge cursor -> in-degree after scatter
// [20000,   340000)  h1    : x@W1 (80000 f32, split-k atomics -> must be zeroed)
// [340000,  2900000) slots : bucketed edge sources, slots[d*CAP+pos]=src
// [2900000, 3220000) a1    : relu(agg1(h1)+b1)
// [3220000, 3540000) g2    : agg2(a1)

__device__ __forceinline__ short f2bf(float f) {  // RNE f32->bf16
  union { float f; unsigned u; } v; v.f = f;
  unsigned r = v.u + 0x7FFFu + ((v.u >> 16) & 1u);
  return (short)(r >> 16);
}

// Bucket edges by destination: 160K int atomics (vs 5.1M f32 atomics before).
__global__ void k_scatter(const int* __restrict__ src, const int* __restrict__ dst,
                          int* __restrict__ cur, int* __restrict__ slots) {
  int e = blockIdx.x * 256 + threadIdx.x;
  if (e >= NE) return;
  int d = dst[e];
  int pos = atomicAdd(&cur[d], 1);
  if (pos < CAP) slots[d * CAP + pos] = src[e];
}

// h1 = x @ W1 via mfma_f32_16x16x32_bf16 (fp32 accumulate), split-k x8.
// Wave = one 16-row x 16-col tile over k-range [kb, kb+klen).
// A frag: lane holds x[m0+(lane&15)][k + quad*8 + j], j=0..7 -- loaded as
//   2x float4 from global (64B segments x16 rows per instr), cvt to bf16.
// B frag: W1 chunk staged once per block into LDS transposed wt[n][k] bf16
//   (stride WTS=648 -> 2-way bank aliasing only); 1x ds_read_b128 per step.
// D: row = quad*4+reg, col = lane&15 (m89-verified) -> 4 atomicAdd/lane.
__global__ __launch_bounds__(256) void k_gemm1(const float* __restrict__ x,
                                               const float* __restrict__ w1,
                                               float* __restrict__ h1) {
  __shared__ short wt[NF * WTS];  // 20736 B
  const int tid = threadIdx.x;
  const int lane = tid & 63;
  const int wv = tid >> 6;
  const int kb = blockIdx.y * KS;
  const int klen = (NN - kb < KS) ? (NN - kb) : KS;   // 640 or 520
  const int nsteps = (klen + 31) >> 5;                // 20 or 17

  // Stage W1[kb..kb+KS) -> wt[n][kk], zero-padded past NN.
  for (int kk = tid; kk < KS; kk += 256) {
    const int kg = kb + kk;
    if (kg < NN) {
      const float4* __restrict__ wr = (const float4*)(w1 + (size_t)kg * NF);
      const float4 a = wr[0], b = wr[1], c = wr[2], d = wr[3];
      wt[0 * WTS + kk] = f2bf(a.x);  wt[1 * WTS + kk] = f2bf(a.y);
      wt[2 * WTS + kk] = f2bf(a.z);  wt[3 * WTS + kk] = f2bf(a.w);
      wt[4 * WTS + kk] = f2bf(b.x);  wt[5 * WTS + kk] = f2bf(b.y);
      wt[6 * WTS + kk] = f2bf(b.z);  wt[7 * WTS + kk] = f2bf(b.w);
      wt[8 * WTS + kk] = f2bf(c.x);  wt[9 * WTS + kk] = f2bf(c.y);
      wt[10 * WTS + kk] = f2bf(c.z); wt[11 * WTS + kk] = f2bf(c.w);
      wt[12 * WTS + kk] = f2bf(d.x); wt[13 * WTS + kk] = f2bf(d.y);
      wt[14 * WTS + kk] = f2bf(d.z); wt[15 * WTS + kk] = f2bf(d.w);
    } else {
#pragma unroll
      for (int n = 0; n < NF; ++n) wt[n * WTS + kk] = 0;
    }
  }
  __syncthreads();

  const int tile = blockIdx.x * 4 + wv;   // 0..315 (313 real)
  const int m0 = tile * 16;
  int arow = m0 + (lane & 15);
  if (arow > NN - 1) arow = NN - 1;       // clamp addr; write guarded below
  const float* __restrict__ xr = x + (size_t)arow * NN + kb;
  const int quad = lane >> 4;
  const short* __restrict__ bp = &wt[(lane & 15) * WTS + quad * 8];

  f32x4 acc = {0.f, 0.f, 0.f, 0.f};
  for (int s = 0; s < nsteps; ++s) {
    const int k0 = s * 32 + quad * 8;     // offset within split (8-aligned)
    bf16x8 a;
    if (kb + k0 < NN) {                   // whole 8-chunk valid (NN%8==0)
      const float4 xa = *(const float4*)(xr + k0);
      const float4 xb = *(const float4*)(xr + k0 + 4);
      a[0] = f2bf(xa.x); a[1] = f2bf(xa.y); a[2] = f2bf(xa.z); a[3] = f2bf(xa.w);
      a[4] = f2bf(xb.x); a[5] = f2bf(xb.y); a[6] = f2bf(xb.z); a[7] = f2bf(xb.w);
    } else {
#pragma unroll
      for (int j = 0; j < 8; ++j) a[j] = 0;
    }
    const bf16x8 b = *(const bf16x8*)(bp + s * 32);  // 16B-aligned ds_read_b128
    acc = __builtin_amdgcn_mfma_f32_16x16x32_bf16(a, b, acc, 0, 0, 0);
  }

  const int col = lane & 15;
#pragma unroll
  for (int r = 0; r < 4; ++r) {
    const int orow = m0 + quad * 4 + r;
    if (orow < NN) atomicAdd(&h1[orow * NF + col], acc[r]);
  }
}

// Per-node gather aggregation (replaces atomic edge-scatter):
//   out[v][j] = inv[v] * sum_{s in bucket(v)} inv[s]*hin[s][j] + inv[v]^2*hin[v][j]
// with inv[v] = rsqrt(deg[v]+1) computed on the fly from cur[].
// One wave per node; 16-lane group per edge (coalesced 64B row reads of hin);
// shfl_xor reduce across the 4 edge subgroups; 16 lanes write 64B. No atomics.
template <int RELU>
__global__ __launch_bounds__(256) void k_gather(const int* __restrict__ slots,
                                                const int* __restrict__ cnt,
                                                const float* __restrict__ bias,
                                                const float* __restrict__ hin,
                                                float* __restrict__ outp) {
  const int tid = threadIdx.x;
  const int lane = tid & 63;
  const int wv = tid >> 6;
  const int v = blockIdx.x * 4 + wv;
  if (v >= NN) return;
  const int j = lane & 15;
  const int eg = lane >> 4;                 // edge subgroup 0..3
  int deg = cnt[v];
  if (deg > CAP) deg = CAP;                 // safety (never hit for this input)
  const int* __restrict__ sl = slots + v * CAP;

  float acc = 0.f;
  int base = 0;
  for (; base + 8 <= deg; base += 8) {      // 2 independent chains per iter
    const int s0 = sl[base + eg];
    const int s1 = sl[base + 4 + eg];
    const float iv0 = rsqrtf((float)cnt[s0] + 1.0f);
    const float iv1 = rsqrtf((float)cnt[s1] + 1.0f);
    acc += iv0 * hin[s0 * NF + j];
    acc += iv1 * hin[s1 * NF + j];
  }
  for (; base < deg; base += 4) {
    const int idx = base + eg;
    if (idx < deg) {
      const int s = sl[idx];
      acc += rsqrtf((float)cnt[s] + 1.0f) * hin[s * NF + j];
    }
  }
  acc += __shfl_xor(acc, 16);               // combine eg bit 0
  acc += __shfl_xor(acc, 32);               // combine eg bit 1

  if (lane < 16) {
    const float ivv = rsqrtf((float)deg + 1.0f);
    float r = ivv * acc + ivv * ivv * hin[v * NF + j];
    if constexpr (RELU) r = fmaxf(r + bias[j], 0.f);
    outp[v * NF + j] = r;
  }
}

// out[row] = log_softmax(g2[row] @ W2 + b2), 4 rows per block, z staged in LDS.
__global__ __launch_bounds__(512) void k_final(const float* __restrict__ g2,
                                               const float* __restrict__ w2,
                                               const float* __restrict__ b2,
                                               float* __restrict__ out) {
  __shared__ float zs[4 * NN];   // 80000 B
  __shared__ float gsh[64];
  __shared__ float red[8 * 4];
  __shared__ float rowmax[4];
  __shared__ float rowoff[4];
  const int tid = threadIdx.x;
  const int lane = tid & 63;
  const int wv = tid >> 6;  // 8 waves
  const int row0 = blockIdx.x * 4;

  if (tid < 64) gsh[tid] = g2[row0 * NF + tid];
  __syncthreads();
  float g[4][NF];
#pragma unroll
  for (int r = 0; r < 4; ++r)
#pragma unroll
    for (int k = 0; k < NF; ++k) g[r][k] = gsh[r * NF + k];

  float mx[4] = {-1e30f, -1e30f, -1e30f, -1e30f};
  for (int jc = tid; jc < NN; jc += 512) {
    float w[NF];
#pragma unroll
    for (int k = 0; k < NF; ++k) w[k] = w2[k * NN + jc];
    const float bb = b2[jc];
#pragma unroll
    for (int r = 0; r < 4; ++r) {
      float z = bb;
#pragma unroll
      for (int k = 0; k < NF; ++k) z = fmaf(g[r][k], w[k], z);
      zs[r * NN + jc] = z;
      mx[r] = fmaxf(mx[r], z);
    }
  }
#pragma unroll
  for (int r = 0; r < 4; ++r) {
    float m = mx[r];
    for (int off = 32; off; off >>= 1) m = fmaxf(m, __shfl_xor(m, off));
    if (lane == 0) red[wv * 4 + r] = m;
  }
  __syncthreads();
  if (tid < 4) {
    float m = red[tid];
#pragma unroll
    for (int w = 1; w < 8; ++w) m = fmaxf(m, red[w * 4 + tid]);
    rowmax[tid] = m;
  }
  __syncthreads();
  const float rm0 = rowmax[0], rm1 = rowmax[1], rm2 = rowmax[2], rm3 = rowmax[3];

  float sm[4] = {0.f, 0.f, 0.f, 0.f};
  for (int jc = tid; jc < NN; jc += 512) {
    sm[0] += __expf(zs[0 * NN + jc] - rm0);
    sm[1] += __expf(zs[1 * NN + jc] - rm1);
    sm[2] += __expf(zs[2 * NN + jc] - rm2);
    sm[3] += __expf(zs[3 * NN + jc] - rm3);
  }
#pragma unroll
  for (int r = 0; r < 4; ++r) {
    float s = sm[r];
    for (int off = 32; off; off >>= 1) s += __shfl_xor(s, off);
    if (lane == 0) red[wv * 4 + r] = s;
  }
  __syncthreads();
  if (tid < 4) {
    float s = red[tid];
#pragma unroll
    for (int w = 1; w < 8; ++w) s += red[w * 4 + tid];
    rowoff[tid] = rowmax[tid] + logf(s);
  }
  __syncthreads();
  const float o0 = rowoff[0], o1 = rowoff[1], o2 = rowoff[2], o3 = rowoff[3];
  for (int jc = tid; jc < NN; jc += 512) {
    out[(size_t)(row0 + 0) * NN + jc] = zs[0 * NN + jc] - o0;
    out[(size_t)(row0 + 1) * NN + jc] = zs[1 * NN + jc] - o1;
    out[(size_t)(row0 + 2) * NN + jc] = zs[2 * NN + jc] - o2;
    out[(size_t)(row0 + 3) * NN + jc] = zs[3 * NN + jc] - o3;
  }
}

extern "C" void kernel_launch(void* const* d_in, const int* in_sizes, int n_in,
                              void* d_out, int out_size, void* d_ws, size_t ws_size,
                              hipStream_t stream) {
  const float* x  = (const float*)d_in[0];
  const int*   src = (const int*)d_in[1];
  const int*   dst = (const int*)d_in[2];
  const float* W1 = (const float*)d_in[3];
  const float* b1 = (const float*)d_in[4];
  const float* W2 = (const float*)d_in[5];
  const float* b2 = (const float*)d_in[6];
  float* out = (float*)d_out;

  char* ws = (char*)d_ws;
  int*   cur   = (int*)(ws);                // [0, 20000)
  float* h1    = (float*)(ws + 20000);      // [20000, 340000)
  int*   slots = (int*)(ws + 340000);       // [340000, 2900000)
  float* a1    = (float*)(ws + 2900000);    // [2900000, 3220000)
  float* g2    = (float*)(ws + 3220000);    // [3220000, 3540000)

  // zero cur + h1 (scatter cursors; split-k atomics accumulate into h1)
  hipMemsetAsync(d_ws, 0, 340000, stream);
  k_scatter<<<(NE + 255) / 256, 256, 0, stream>>>(src, dst, cur, slots);
  k_gemm1<<<dim3(79, 8), 256, 0, stream>>>(x, W1, h1);
  k_gather<1><<<NN / 4, 256, 0, stream>>>(slots, cur, b1, h1, a1);
  k_gather<0><<<NN / 4, 256, 0, stream>>>(slots, cur, nullptr, a1, g2);
  k_final<<<NN / 4, 512, 0, stream>>>(g2, W2, b2, out);
}